// Round 3
// baseline (12428.178 us; speedup 1.0000x reference)
//
#include <hip/hip_runtime.h>
#include <hip/hip_bf16.h>
#include <math.h>

typedef __hip_bfloat16 bf16;

#define Bb 64
#define Hh 56
#define Ww 56
#define Cc 128
#define WS 7
#define SHIFT 3
#define NH 4
#define HD 32
#define Nn 49
#define NW 64
#define HID 512

__device__ __forceinline__ float b2f(bf16 v) { return __bfloat162float(v); }
__device__ __forceinline__ bf16 f2b(float v) { return __float2bfloat16(v); }

// ---------------- Kernel 1: shifted-window attention + proj + residual ----------------
// one block per window (B*NW = 4096), 256 threads (4 waves, one wave per head)
// fp32 in, fp32 out.
__global__ __launch_bounds__(256) void attn_kernel(
    const float* __restrict__ x,          // (B, 3136, 128) shortcut
    const float* __restrict__ x_norm1,    // (B, 3136, 128)
    const float* __restrict__ qkv_w,      // (384, 128)
    const float* __restrict__ qkv_b,      // (384)
    const float* __restrict__ rel_bias,   // (169, 4)
    const float* __restrict__ proj_w,     // (128, 128)
    const float* __restrict__ proj_b,     // (128)
    const float* __restrict__ attn_mask,  // (64, 49, 49)
    const int*  __restrict__ rel_index,   // (49, 49)
    float* __restrict__ out)              // (B, 3136, 128) = x + attn_out
{
    __shared__ float winf[Nn * Cc];           // window tile (fp32); reused as attn_out
    __shared__ bf16  qs[Nn * Cc];
    __shared__ bf16  ks[Nn * Cc];
    __shared__ bf16  vs[Nn * Cc];

    const int blk = blockIdx.x;
    const int b   = blk >> 6;    // / NW
    const int nw  = blk & 63;
    const int wh  = nw >> 3;
    const int wwi = nw & 7;
    const int tid = threadIdx.x;

    // ---- gather shifted window of x_norm1 into LDS (fp32) ----
    for (int idx = tid; idx < Nn * Cc; idx += 256) {
        int t = idx >> 7;       // token 0..48
        int c = idx & 127;
        int i = t / WS, j = t - i * WS;
        int hh = wh * WS + i + SHIFT; if (hh >= Hh) hh -= Hh;
        int wp = wwi * WS + j + SHIFT; if (wp >= Ww) wp -= Ww;
        size_t src = ((size_t)b * (Hh * Ww) + hh * Ww + wp) * Cc + c;
        winf[idx] = x_norm1[src];
    }
    __syncthreads();

    // ---- QKV: (49x128) @ (128x384)^T + b ----
    for (int idx = tid; idx < Nn * 3 * Cc; idx += 256) {
        int t  = idx / 384;
        int oc = idx - t * 384;
        float acc = qkv_b[oc];
        const float* wrow = qkv_w + oc * Cc;
        const float* wr   = winf + t * Cc;
        #pragma unroll 8
        for (int k = 0; k < Cc; ++k) acc += wr[k] * wrow[k];
        int g = oc >> 7;          // 0=q 1=k 2=v
        int c = oc & 127;         // = head*32 + d
        bf16 hv = f2b(acc);
        if (g == 0)      qs[t * Cc + c] = hv;
        else if (g == 1) ks[t * Cc + c] = hv;
        else             vs[t * Cc + c] = hv;
    }
    __syncthreads();

    // ---- attention: wave w = head w; lane i = query row i ----
    {
        const int head = tid >> 6;
        const int lane = tid & 63;
        if (lane < Nn) {
            float qreg[HD];
            #pragma unroll
            for (int d = 0; d < HD; ++d)
                qreg[d] = b2f(qs[lane * Cc + head * HD + d]) * 0.17677669529663689f; // HD^-0.5

            float s[Nn];
            const int*   ri = rel_index + lane * Nn;
            const float* mk = attn_mask + ((size_t)nw * Nn + lane) * Nn;
            for (int m = 0; m < Nn; ++m) {
                float acc = 0.f;
                const bf16* kr = ks + m * Cc + head * HD;
                #pragma unroll
                for (int d = 0; d < HD; ++d) acc += qreg[d] * b2f(kr[d]);
                acc += rel_bias[ri[m] * NH + head] + mk[m];
                s[m] = acc;
            }
            float mx = s[0];
            #pragma unroll
            for (int m = 1; m < Nn; ++m) mx = fmaxf(mx, s[m]);
            float l = 0.f;
            #pragma unroll
            for (int m = 0; m < Nn; ++m) { s[m] = __expf(s[m] - mx); l += s[m]; }
            float inv = 1.f / l;

            float o[HD];
            #pragma unroll
            for (int d = 0; d < HD; ++d) o[d] = 0.f;
            for (int m = 0; m < Nn; ++m) {
                float p = s[m];
                const bf16* vr = vs + m * Cc + head * HD;
                #pragma unroll
                for (int d = 0; d < HD; ++d) o[d] += p * b2f(vr[d]);
            }
            // winf now dead (QKV consumed it) -> reuse as attn_out
            #pragma unroll
            for (int d = 0; d < HD; ++d) winf[lane * Cc + head * HD + d] = o[d] * inv;
        }
    }
    __syncthreads();

    // ---- proj + shortcut, scatter back (scatter pos == gather pos) ----
    for (int idx = tid; idx < Nn * Cc; idx += 256) {
        int t  = idx >> 7;
        int oc = idx & 127;
        float acc = proj_b[oc];
        const float* wrow = proj_w + oc * Cc;
        const float* ar   = winf + t * Cc;
        #pragma unroll 8
        for (int k = 0; k < Cc; ++k) acc += ar[k] * wrow[k];
        int i = t / WS, j = t - i * WS;
        int hh = wh * WS + i + SHIFT; if (hh >= Hh) hh -= Hh;
        int wp = wwi * WS + j + SHIFT; if (wp >= Ww) wp -= Ww;
        size_t addr = ((size_t)b * (Hh * Ww) + hh * Ww + wp) * Cc + oc;
        out[addr] = x[addr] + acc;
    }
}

// ---------------- Kernel 2: LN -> fc1 -> GELU -> fc2 -> residual (in-place on out) ----------------
// one block per 16 tokens, 256 threads
__global__ __launch_bounds__(256) void mlp_kernel(
    const float* __restrict__ norm2_w, const float* __restrict__ norm2_b,
    const float* __restrict__ fc1_w,   const float* __restrict__ fc1_b,
    const float* __restrict__ fc2_w,   const float* __restrict__ fc2_b,
    float* __restrict__ xio)           // (tokens, 128), read x_new, write final
{
    __shared__ float xt[16 * Cc];      // 8 KB
    __shared__ float ht[16 * Cc];      // 8 KB (LN output)
    __shared__ float gg[16 * HID];     // 32 KB (GELU output)
    __shared__ float redS[16][17], redQ[16][17];
    __shared__ float mu_s[16], rs_s[16];

    const int tid = threadIdx.x;
    const size_t base = (size_t)blockIdx.x * 16 * Cc;

    for (int idx = tid; idx < 16 * Cc; idx += 256) xt[idx] = xio[base + idx];
    __syncthreads();

    // LN stats: 16 threads per token
    {
        int t = tid >> 4, p = tid & 15;
        float s1 = 0.f, s2 = 0.f;
        const float* xr = xt + t * Cc + p * 8;
        #pragma unroll
        for (int k = 0; k < 8; ++k) { float v = xr[k]; s1 += v; s2 += v * v; }
        redS[t][p] = s1; redQ[t][p] = s2;
    }
    __syncthreads();
    if (tid < 16) {
        float s1 = 0.f, s2 = 0.f;
        #pragma unroll
        for (int p = 0; p < 16; ++p) { s1 += redS[tid][p]; s2 += redQ[tid][p]; }
        float mu  = s1 * (1.f / Cc);
        float var = s2 * (1.f / Cc) - mu * mu;
        mu_s[tid] = mu;
        rs_s[tid] = rsqrtf(var + 1e-5f);
    }
    __syncthreads();
    for (int idx = tid; idx < 16 * Cc; idx += 256) {
        int t = idx >> 7, c = idx & 127;
        ht[idx] = (xt[idx] - mu_s[t]) * rs_s[t] * norm2_w[c] + norm2_b[c];
    }
    __syncthreads();

    // fc1 + GELU: each thread owns 2 hidden units across all 16 tokens
    #pragma unroll
    for (int oo = 0; oo < 2; ++oo) {
        int o = tid * 2 + oo;
        const float* wrow = fc1_w + o * Cc;
        float bb = fc1_b[o];
        float acc[16];
        #pragma unroll
        for (int t = 0; t < 16; ++t) acc[t] = bb;
        #pragma unroll 4
        for (int k = 0; k < Cc; ++k) {
            float wv = wrow[k];
            #pragma unroll
            for (int t = 0; t < 16; ++t) acc[t] += wv * ht[t * Cc + k];
        }
        #pragma unroll
        for (int t = 0; t < 16; ++t) {
            float a = acc[t];
            gg[t * HID + o] = 0.5f * a * (1.f + erff(a * 0.70710678118654752f));
        }
    }
    __syncthreads();

    // fc2 + residual, in-place
    for (int idx = tid; idx < 16 * Cc; idx += 256) {
        int t = idx >> 7, oc = idx & 127;
        float acc = fc2_b[oc];
        const float* wrow = fc2_w + (size_t)oc * HID;
        const float* gr   = gg + t * HID;
        #pragma unroll 8
        for (int k = 0; k < HID; ++k) acc += gr[k] * wrow[k];
        xio[base + idx] = xt[idx] + acc;
    }
}

extern "C" void kernel_launch(void* const* d_in, const int* in_sizes, int n_in,
                              void* d_out, int out_size, void* d_ws, size_t ws_size,
                              hipStream_t stream) {
    const float* x         = (const float*)d_in[0];
    const float* x_norm1   = (const float*)d_in[1];
    const float* qkv_w     = (const float*)d_in[2];
    const float* qkv_b     = (const float*)d_in[3];
    const float* rel_bias  = (const float*)d_in[4];
    const float* proj_w    = (const float*)d_in[5];
    const float* proj_b    = (const float*)d_in[6];
    const float* norm2_w   = (const float*)d_in[7];
    const float* norm2_b   = (const float*)d_in[8];
    const float* fc1_w     = (const float*)d_in[9];
    const float* fc1_b     = (const float*)d_in[10];
    const float* fc2_w     = (const float*)d_in[11];
    const float* fc2_b     = (const float*)d_in[12];
    const float* attn_mask = (const float*)d_in[13];
    const int*   rel_index = (const int*)d_in[14];
    float* out = (float*)d_out;

    attn_kernel<<<Bb * NW, 256, 0, stream>>>(x, x_norm1, qkv_w, qkv_b, rel_bias,
                                             proj_w, proj_b, attn_mask, rel_index, out);

    const int tokens = Bb * Hh * Ww;           // 200704
    mlp_kernel<<<tokens / 16, 256, 0, stream>>>(norm2_w, norm2_b, fc1_w, fc1_b,
                                                fc2_w, fc2_b, out);
}

// Round 4
// 1346.172 us; speedup vs baseline: 9.2322x; 9.2322x over previous
//
#include <hip/hip_runtime.h>
#include <hip/hip_bf16.h>
#include <math.h>

typedef __hip_bfloat16 bf16;
typedef __attribute__((ext_vector_type(8))) short short8;
typedef __attribute__((ext_vector_type(4))) float f32x4;

#define Bb 64
#define Hh 56
#define Ww 56
#define Cc 128
#define WS 7
#define SHIFT 3
#define NH 4
#define HD 32
#define Nn 49
#define NW 64
#define HID 512

// ws layout (shorts): qkv_w @0 (49152), proj_w @49152 (16384), fc1_w @65536 (65536), fc2_w @131072 (65536)
// biasT (float) @ byte 393216: [4][49][49]
#define WS_QKV 0
#define WS_PROJ 49152
#define WS_FC1 65536
#define WS_FC2 131072
#define WS_BIAS_BYTES 393216

__device__ __forceinline__ short fb(float v) { return __builtin_bit_cast(short, __float2bfloat16(v)); }

// ---------------- prep: weights fp32->bf16 into ws; gather rel-bias table ----------------
__global__ __launch_bounds__(256) void prep_kernel(
    const float* __restrict__ qkv_w, const float* __restrict__ proj_w,
    const float* __restrict__ fc1_w, const float* __restrict__ fc2_w,
    const float* __restrict__ rel_bias, const int* __restrict__ rel_index,
    short* __restrict__ wsb, float* __restrict__ biasT)
{
    int t = blockIdx.x * 256 + threadIdx.x;
    if (t < 49152)       wsb[t] = fb(qkv_w[t]);
    else if (t < 65536)  wsb[t] = fb(proj_w[t - 49152]);
    else if (t < 131072) wsb[t] = fb(fc1_w[t - 65536]);
    else if (t < 196608) wsb[t] = fb(fc2_w[t - 131072]);
    if (t < 4 * Nn * Nn) {
        int h = t / (Nn * Nn), r = t - h * (Nn * Nn);
        biasT[t] = rel_bias[rel_index[r] * NH + h];
    }
}

// ---------------- attention: one block per window, 4 waves ----------------
// LDS strides (elements, all %8==0 for 16B ds_read alignment, ~2-way banks):
#define SW 136   // win/ao row stride (128 cols)
#define SQ 40    // qs/ks row stride (32 cols)
#define SV 72    // vT row stride (64 cols)
#define SP 72    // p row stride (64 cols)

__global__ __launch_bounds__(256, 1) void attn_kernel(
    const float* __restrict__ x,          // (B,3136,128) shortcut
    const float* __restrict__ x_norm1,    // (B,3136,128)
    const float* __restrict__ qkv_b,      // (384)
    const float* __restrict__ proj_b,     // (128)
    const float* __restrict__ attn_mask,  // (64,49,49)
    const short* __restrict__ wsb,        // bf16 weights
    const float* __restrict__ biasT,      // (4,49,49)
    float* __restrict__ out)
{
    __shared__ short win[64 * SW];            // window tile; reused as attn_out
    __shared__ short qs[NH * 64 * SQ];
    __shared__ short ks[NH * 64 * SQ];
    __shared__ short vT[NH * HD * SV];
    __shared__ short pm[NH * 64 * SP];

    const int blk = blockIdx.x;
    const int b   = blk >> 6;
    const int nw  = blk & 63;
    const int wh  = nw >> 3;
    const int wwi = nw & 7;
    const int tid  = threadIdx.x;
    const int wave = tid >> 6;
    const int lane = tid & 63;
    const int quad = lane >> 4;
    const int l16  = lane & 15;

    // ---- gather shifted window (rows 49..63 zero) ----
    for (int idx = tid; idx < 64 * Cc; idx += 256) {
        int t = idx >> 7, c = idx & 127;
        float v = 0.f;
        if (t < Nn) {
            int i = t / WS, j = t - i * WS;
            int hh = wh * WS + i + SHIFT; if (hh >= Hh) hh -= Hh;
            int wp = wwi * WS + j + SHIFT; if (wp >= Ww) wp -= Ww;
            v = x_norm1[((size_t)b * (Hh * Ww) + hh * Ww + wp) * Cc + c];
        }
        win[t * SW + c] = fb(v);
    }
    __syncthreads();

    // ---- QKV: wave w = m-tile w (tokens 16w..16w+15), 24 n-tiles, K=128 ----
    {
        short8 a1[4];
        #pragma unroll
        for (int kk = 0; kk < 4; ++kk)
            a1[kk] = *(const short8*)&win[(wave * 16 + l16) * SW + kk * 32 + quad * 8];
        const short* wq = wsb + WS_QKV;
        for (int nt = 0; nt < 24; ++nt) {
            f32x4 c = {0.f, 0.f, 0.f, 0.f};
            int n = nt * 16 + l16;
            #pragma unroll
            for (int kk = 0; kk < 4; ++kk) {
                short8 bf = *(const short8*)&wq[n * Cc + kk * 32 + quad * 8];
                c = __builtin_amdgcn_mfma_f32_16x16x32_bf16(a1[kk], bf, c, 0, 0, 0);
            }
            int oc = n;
            int g = oc >> 7, ch = oc & 127, head = ch >> 5, d = ch & 31;
            float bias = qkv_b[oc];
            #pragma unroll
            for (int r = 0; r < 4; ++r) {
                int tok = wave * 16 + quad * 4 + r;
                float val = c[r] + bias;
                if (g == 0)      qs[head * 64 * SQ + tok * SQ + d] = fb(val * 0.17677669529663689f);
                else if (g == 1) ks[head * 64 * SQ + tok * SQ + d] = fb(val);
                else             vT[head * HD * SV + d * SV + tok] = fb(val);
            }
        }
    }
    __syncthreads();

    // ---- scores + softmax: wave = head ----
    {
        const int head = wave;
        const float* bT = biasT + head * (Nn * Nn);
        const float* mk = attn_mask + nw * (Nn * Nn);
        short8 bk[4];
        #pragma unroll
        for (int nt = 0; nt < 4; ++nt)
            bk[nt] = *(const short8*)&ks[head * 64 * SQ + (nt * 16 + l16) * SQ + quad * 8];

        for (int mt = 0; mt < 4; ++mt) {
            short8 aq = *(const short8*)&qs[head * 64 * SQ + (mt * 16 + l16) * SQ + quad * 8];
            f32x4 sc[4];
            #pragma unroll
            for (int nt = 0; nt < 4; ++nt) {
                f32x4 z = {0.f, 0.f, 0.f, 0.f};
                sc[nt] = __builtin_amdgcn_mfma_f32_16x16x32_bf16(aq, bk[nt], z, 0, 0, 0);
            }
            #pragma unroll
            for (int r = 0; r < 4; ++r) {
                int row = mt * 16 + quad * 4 + r;
                bool rowv = row < Nn;
                float v[4];
                #pragma unroll
                for (int nt = 0; nt < 4; ++nt) {
                    int col = nt * 16 + l16;
                    float s = sc[nt][r];
                    if (rowv && col < Nn) s += bT[row * Nn + col] + mk[row * Nn + col];
                    else s = -1e30f;
                    v[nt] = s;
                }
                float mx = fmaxf(fmaxf(v[0], v[1]), fmaxf(v[2], v[3]));
                #pragma unroll
                for (int off = 1; off < 16; off <<= 1) mx = fmaxf(mx, __shfl_xor(mx, off, 64));
                float e[4]; float sum = 0.f;
                #pragma unroll
                for (int nt = 0; nt < 4; ++nt) { e[nt] = __expf(v[nt] - mx); sum += e[nt]; }
                #pragma unroll
                for (int off = 1; off < 16; off <<= 1) sum += __shfl_xor(sum, off, 64);
                float inv = 1.f / sum;
                #pragma unroll
                for (int nt = 0; nt < 4; ++nt)
                    pm[head * 64 * SP + row * SP + nt * 16 + l16] = fb(e[nt] * inv);
            }
        }
    }
    // pm is wave-private; vT was synced above — no barrier needed here.

    // ---- PV: O[64 x 32] per head ----
    {
        const int head = wave;
        f32x4 o[4][2];
        #pragma unroll
        for (int mt = 0; mt < 4; ++mt)
            #pragma unroll
            for (int nt = 0; nt < 2; ++nt) o[mt][nt] = f32x4{0.f, 0.f, 0.f, 0.f};
        #pragma unroll
        for (int kstep = 0; kstep < 2; ++kstep) {
            short8 bv[2];
            #pragma unroll
            for (int nt = 0; nt < 2; ++nt)
                bv[nt] = *(const short8*)&vT[head * HD * SV + (nt * 16 + l16) * SV + kstep * 32 + quad * 8];
            #pragma unroll
            for (int mt = 0; mt < 4; ++mt) {
                short8 ap = *(const short8*)&pm[head * 64 * SP + (mt * 16 + l16) * SP + kstep * 32 + quad * 8];
                #pragma unroll
                for (int nt = 0; nt < 2; ++nt)
                    o[mt][nt] = __builtin_amdgcn_mfma_f32_16x16x32_bf16(ap, bv[nt], o[mt][nt], 0, 0, 0);
            }
        }
        // write attn_out into win (safe: all win reads finished before the post-QKV barrier)
        #pragma unroll
        for (int mt = 0; mt < 4; ++mt)
            #pragma unroll
            for (int nt = 0; nt < 2; ++nt)
                #pragma unroll
                for (int r = 0; r < 4; ++r) {
                    int tok = mt * 16 + quad * 4 + r;
                    int cch = head * HD + nt * 16 + l16;
                    win[tok * SW + cch] = fb(o[mt][nt][r]);
                }
    }
    __syncthreads();

    // ---- proj + residual + scatter ----
    {
        short8 a[4];
        #pragma unroll
        for (int kk = 0; kk < 4; ++kk)
            a[kk] = *(const short8*)&win[(wave * 16 + l16) * SW + kk * 32 + quad * 8];
        const short* wp_ = wsb + WS_PROJ;
        for (int nt2 = 0; nt2 < 8; ++nt2) {
            int n = nt2 * 16 + l16;
            f32x4 c = {0.f, 0.f, 0.f, 0.f};
            #pragma unroll
            for (int kk = 0; kk < 4; ++kk) {
                short8 bf = *(const short8*)&wp_[n * Cc + kk * 32 + quad * 8];
                c = __builtin_amdgcn_mfma_f32_16x16x32_bf16(a[kk], bf, c, 0, 0, 0);
            }
            float pb = proj_b[n];
            #pragma unroll
            for (int r = 0; r < 4; ++r) {
                int tok = wave * 16 + quad * 4 + r;
                if (tok < Nn) {
                    int i = tok / WS, j = tok - i * WS;
                    int hh = wh * WS + i + SHIFT; if (hh >= Hh) hh -= Hh;
                    int wpp = wwi * WS + j + SHIFT; if (wpp >= Ww) wpp -= Ww;
                    size_t addr = ((size_t)b * (Hh * Ww) + hh * Ww + wpp) * Cc + n;
                    out[addr] = x[addr] + c[r] + pb;
                }
            }
        }
    }
}

// ---------------- MLP: 64 tokens/block, LN -> fc1 -> GELU -> fc2 -> residual ----------------
#define SH 136   // hb row stride
#define SG 40    // g tile row stride

__global__ __launch_bounds__(256) void mlp_kernel(
    const float* __restrict__ norm2_w, const float* __restrict__ norm2_b,
    const float* __restrict__ fc1_b,   const float* __restrict__ fc2_b,
    const short* __restrict__ wsb,
    float* __restrict__ xio)
{
    __shared__ short hb[64 * SH];
    __shared__ short gt[NH][16 * SG];
    __shared__ float b1[HID], b2[Cc];

    const int tid  = threadIdx.x;
    const int wave = tid >> 6;
    const int lane = tid & 63;
    const int quad = lane >> 4;
    const int l16  = lane & 15;
    const size_t base = (size_t)blockIdx.x * 64 * Cc;

    for (int i = tid; i < HID; i += 256) b1[i] = fc1_b[i];
    if (tid < Cc) b2[tid] = fc2_b[tid];

    // ---- LN: 4 threads per token ----
    {
        int t = tid >> 2, qtr = tid & 3;
        const float* xr = xio + base + t * Cc + qtr * 32;
        float vals[32];
        float s1 = 0.f, s2 = 0.f;
        #pragma unroll
        for (int k8 = 0; k8 < 8; ++k8) {
            f32x4 v4 = *(const f32x4*)&xr[k8 * 4];
            #pragma unroll
            for (int u = 0; u < 4; ++u) {
                float v = v4[u];
                vals[k8 * 4 + u] = v;
                s1 += v; s2 += v * v;
            }
        }
        s1 += __shfl_xor(s1, 1, 64); s1 += __shfl_xor(s1, 2, 64);
        s2 += __shfl_xor(s2, 1, 64); s2 += __shfl_xor(s2, 2, 64);
        float mu = s1 * (1.f / Cc);
        float var = s2 * (1.f / Cc) - mu * mu;
        float rs = rsqrtf(var + 1e-5f);
        #pragma unroll
        for (int k = 0; k < 32; ++k) {
            int c = qtr * 32 + k;
            hb[t * SH + c] = fb((vals[k] - mu) * rs * norm2_w[c] + norm2_b[c]);
        }
    }
    __syncthreads();

    // ---- fc1 -> GELU -> fc2 (chunked over hidden) ----
    {
        short8 a1[4];
        #pragma unroll
        for (int kk = 0; kk < 4; ++kk)
            a1[kk] = *(const short8*)&hb[(wave * 16 + l16) * SH + kk * 32 + quad * 8];
        const short* w1 = wsb + WS_FC1;
        const short* w2 = wsb + WS_FC2;
        f32x4 acc[8];
        #pragma unroll
        for (int n2 = 0; n2 < 8; ++n2) acc[n2] = f32x4{0.f, 0.f, 0.f, 0.f};

        for (int h = 0; h < 16; ++h) {
            #pragma unroll
            for (int nt = 0; nt < 2; ++nt) {
                int n = h * 32 + nt * 16 + l16;
                f32x4 c = {0.f, 0.f, 0.f, 0.f};
                #pragma unroll
                for (int kk = 0; kk < 4; ++kk) {
                    short8 bf = *(const short8*)&w1[n * Cc + kk * 32 + quad * 8];
                    c = __builtin_amdgcn_mfma_f32_16x16x32_bf16(a1[kk], bf, c, 0, 0, 0);
                }
                float bb = b1[n];
                #pragma unroll
                for (int r = 0; r < 4; ++r) {
                    float v = c[r] + bb;
                    float g = 0.5f * v * (1.f + erff(v * 0.70710678118654752f));
                    gt[wave][(quad * 4 + r) * SG + nt * 16 + l16] = fb(g);
                }
            }
            // wave-private tile: lockstep write->read, no block barrier needed
            short8 a2 = *(const short8*)&gt[wave][l16 * SG + quad * 8];
            #pragma unroll
            for (int n2 = 0; n2 < 8; ++n2) {
                short8 bf = *(const short8*)&w2[(n2 * 16 + l16) * HID + h * 32 + quad * 8];
                acc[n2] = __builtin_amdgcn_mfma_f32_16x16x32_bf16(a2, bf, acc[n2], 0, 0, 0);
            }
        }
        // epilogue: + bias + residual, in place
        #pragma unroll
        for (int n2 = 0; n2 < 8; ++n2) {
            int cch = n2 * 16 + l16;
            float bb = b2[cch];
            #pragma unroll
            for (int r = 0; r < 4; ++r) {
                int tok = wave * 16 + quad * 4 + r;
                size_t ad = base + (size_t)tok * Cc + cch;
                xio[ad] = xio[ad] + acc[n2][r] + bb;
            }
        }
    }
}

extern "C" void kernel_launch(void* const* d_in, const int* in_sizes, int n_in,
                              void* d_out, int out_size, void* d_ws, size_t ws_size,
                              hipStream_t stream) {
    const float* x         = (const float*)d_in[0];
    const float* x_norm1   = (const float*)d_in[1];
    const float* qkv_w     = (const float*)d_in[2];
    const float* qkv_b     = (const float*)d_in[3];
    const float* rel_bias  = (const float*)d_in[4];
    const float* proj_w    = (const float*)d_in[5];
    const float* proj_b    = (const float*)d_in[6];
    const float* norm2_w   = (const float*)d_in[7];
    const float* norm2_b   = (const float*)d_in[8];
    const float* fc1_w     = (const float*)d_in[9];
    const float* fc1_b     = (const float*)d_in[10];
    const float* fc2_w     = (const float*)d_in[11];
    const float* fc2_b     = (const float*)d_in[12];
    const float* attn_mask = (const float*)d_in[13];
    const int*   rel_index = (const int*)d_in[14];
    float* out = (float*)d_out;

    short* wsb   = (short*)d_ws;
    float* biasT = (float*)((char*)d_ws + WS_BIAS_BYTES);

    prep_kernel<<<768, 256, 0, stream>>>(qkv_w, proj_w, fc1_w, fc2_w,
                                         rel_bias, rel_index, wsb, biasT);

    attn_kernel<<<Bb * NW, 256, 0, stream>>>(x, x_norm1, qkv_b, proj_b,
                                             attn_mask, wsb, biasT, out);

    mlp_kernel<<<Bb * Hh * Ww / 64, 256, 0, stream>>>(norm2_w, norm2_b, fc1_b,
                                                      fc2_b, wsb, out);
}